// Round 5
// baseline (61.762 us; speedup 1.0000x reference)
//
#include <hip/hip_runtime.h>
#include <math.h>

#define NUM_H 256
#define NP    64        // poles per h
#define LL    8192      // sequence length
#define NHALF 4096      // LL/2 (complex FFT size)
#define NTA   256       // threads, Cauchy kernel
#define NTB   1024      // threads, FFT kernel

typedef float v2f __attribute__((ext_vector_type(2)));

// v_sin_f32 / v_cos_f32 take input in REVOLUTIONS (D = sin(S0 * 2pi)).

// ---------------- Kernel A: Cauchy sum + Woodbury -> spectrum ----------------
// Pole-pair packing: each lane owns ONE bin; every packed op processes TWO
// poles. Packed constants come pre-paired from LDS (ds_read_b128 -> adjacent
// VGPRs = natural VOP3P operands, no splat movs). One rcp per (bin,pole) via
// 1/d1 = d2*rcp(d1*d2).
__global__ __launch_bounds__(NTA, 6)
void cauchy_phase(const float* __restrict__ w_ri,
                  const float* __restrict__ p_ri,
                  const float* __restrict__ q_ri,
                  const float* __restrict__ B_ri,
                  const float* __restrict__ C_ri,
                  const float* __restrict__ log_dt,
                  float*       __restrict__ spec,   // (H, 4096) float2 rows (= d_out)
                  float2*      __restrict__ nyq)    // (H,) Nyquist bins (= d_ws)
{
    __shared__ float4 s_wd[NP / 2];    // {wi_e, wi_o, wz_e, wz_o}
    __shared__ float2 s_wx[NP / 2];    // {-wr_e, -wr_o}
    __shared__ float4 s_v00[NP / 2];   // {vr_e, vr_o, vi_e, vi_o}  (B*conj(C))
    __shared__ float4 s_v01[NP / 2];   // p*conj(C)
    __shared__ float4 s_v10[NP / 2];   // B*conj(q)
    __shared__ float4 s_v11[NP / 2];   // p*conj(q)

    const int h     = blockIdx.y;
    const int chunk = blockIdx.x;      // 16 chunks of 256 bins
    const int tid   = threadIdx.x;
    const float dt  = expf(log_dt[h]);

    if (tid < NP) {
        const int n = tid;
        const int k = n >> 1, o = n & 1;
        const float2 w = ((const float2*)w_ri)[h * NP + n];
        const float2 p = ((const float2*)p_ri)[h * NP + n];
        const float2 q = ((const float2*)q_ri)[h * NP + n];
        const float2 B = ((const float2*)B_ri)[h * NP + n];
        const float2 C = ((const float2*)C_ri)[h * NP + n];
        const float wr = w.x * dt, wi = w.y * dt;
        ((float*)&s_wd[k])[o]     = wi;
        ((float*)&s_wd[k])[2 + o] = wr * wr;
        ((float*)&s_wx[k])[o]     = -wr;
        ((float*)&s_v00[k])[o]     = B.x * C.x + B.y * C.y;   // Re B*conj(C)
        ((float*)&s_v00[k])[2 + o] = B.y * C.x - B.x * C.y;   // Im
        ((float*)&s_v01[k])[o]     = p.x * C.x + p.y * C.y;
        ((float*)&s_v01[k])[2 + o] = p.y * C.x - p.x * C.y;
        ((float*)&s_v10[k])[o]     = B.x * q.x + B.y * q.y;
        ((float*)&s_v10[k])[2 + o] = B.y * q.x - B.x * q.y;
        ((float*)&s_v11[k])[o]     = p.x * q.x + p.y * q.y;
        ((float*)&s_v11[k])[2 + o] = p.y * q.x - p.x * q.y;
    }
    __syncthreads();

    const int l = (chunk << 8) + tid;       // 0..4095
    // y = Im(z) = 2*tan(pi*l/L); rev = l/16384 (exact dyadic)
    const float rev = (float)l * 6.103515625e-5f;
    const float sn  = __builtin_amdgcn_sinf(rev);
    const float cn  = fmaxf(__builtin_amdgcn_cosf(rev), 4.3711388e-8f);
    const float y   = 2.0f * sn * __builtin_amdgcn_rcpf(cn);
    const v2f   y2  = {y, y};

    v2f a0 = 0.f, a1 = 0.f, a2 = 0.f, a3 = 0.f;
    v2f a4 = 0.f, a5 = 0.f, a6 = 0.f, a7 = 0.f;
    #pragma unroll 2
    for (int k = 0; k < NP / 2; ++k) {
        const float4 wd = s_wd[k];
        const float2 wx = s_wx[k];
        const v2f wi2 = {wd.x, wd.y};
        const v2f wz2 = {wd.z, wd.w};
        const v2f wx2 = {wx.x, wx.y};
        const v2f t1 = y2 - wi2;
        const v2f t2 = y2 + wi2;
        const v2f d1 = t1 * t1 + wz2;
        const v2f d2 = t2 * t2 + wz2;
        const v2f dd = d1 * d2;
        const v2f ir = {__builtin_amdgcn_rcpf(dd.x), __builtin_amdgcn_rcpf(dd.y)};
        const v2f i1 = d2 * ir;
        const v2f i2 = d1 * ir;
        const v2f u1 = t1 * i1;
        const v2f u2 = t2 * i2;
        const v2f sI = i1 + i2, dI = i1 - i2;
        const v2f Sr = wx2 * sI;
        const v2f Si = -(u1 + u2);
        const v2f Dr = u1 - u2;
        const v2f Di = wx2 * dI;
        const float4 v00 = s_v00[k];
        const float4 v01 = s_v01[k];
        const float4 v10 = s_v10[k];
        const float4 v11 = s_v11[k];
        a0 += (v2f){v00.x, v00.y} * Sr + (v2f){v00.z, v00.w} * Dr;
        a1 += (v2f){v00.x, v00.y} * Si + (v2f){v00.z, v00.w} * Di;
        a2 += (v2f){v01.x, v01.y} * Sr + (v2f){v01.z, v01.w} * Dr;
        a3 += (v2f){v01.x, v01.y} * Si + (v2f){v01.z, v01.w} * Di;
        a4 += (v2f){v10.x, v10.y} * Sr + (v2f){v10.z, v10.w} * Dr;
        a5 += (v2f){v10.x, v10.y} * Si + (v2f){v10.z, v10.w} * Di;
        a6 += (v2f){v11.x, v11.y} * Sr + (v2f){v11.z, v11.w} * Dr;
        a7 += (v2f){v11.x, v11.y} * Si + (v2f){v11.z, v11.w} * Di;
    }

    // horizontal add over the pole-pair halves, then Woodbury
    {
        const float a00r = (a0.x + a0.y) * dt, a00i = (a1.x + a1.y) * dt;
        const float a01r = (a2.x + a2.y) * dt, a01i = (a3.x + a3.y) * dt;
        const float a10r = (a4.x + a4.y) * dt, a10i = (a5.x + a5.y) * dt;
        const float a11r = (a6.x + a6.y) * dt, a11i = (a7.x + a7.y) * dt;
        const float numr = a01r * a10r - a01i * a10i;
        const float numi = a01r * a10i + a01i * a10r;
        const float dwr = 1.f + a11r, dwi = a11i;
        const float idw = __builtin_amdgcn_rcpf(dwr * dwr + dwi * dwi);
        const float qr = (numr * dwr + numi * dwi) * idw;
        const float qi = (numi * dwr - numr * dwi) * idw;
        const float kfr = a00r - qr, kfi = a00i - qi;
        const float fi  = 0.5f * y;        // 2/(1+nodes) = 1 + i*tan(pi*l/L)
        float2* grow = (float2*)(spec + (size_t)h * LL);
        grow[l] = make_float2(kfr - kfi * fi, kfi + kfr * fi);
    }

    // ---- Nyquist bin l=4096: one pole per lane of wave 0 of chunk 15 ----
    if (chunk == 15 && tid < 64) {
        const int n = tid;
        const int k = n >> 1, o = n & 1;
        const float wi = ((float*)&s_wd[k])[o];
        const float wz = ((float*)&s_wd[k])[2 + o];
        const float wx = ((float*)&s_wx[k])[o];
        const float4 vv00 = s_v00[k];
        const float4 vv01 = s_v01[k];
        const float4 vv10 = s_v10[k];
        const float4 vv11 = s_v11[k];
        const float v00r = o ? vv00.y : vv00.x, v00i = o ? vv00.w : vv00.z;
        const float v01r = o ? vv01.y : vv01.x, v01i = o ? vv01.w : vv01.z;
        const float v10r = o ? vv10.y : vv10.x, v10i = o ? vv10.w : vv10.z;
        const float v11r = o ? vv11.y : vv11.x, v11i = o ? vv11.w : vv11.z;
        // rev = 0.25 -> cos = 0 exactly; clamp reproduces reference's f32 z ~ 4.58e7
        const float y4 = 2.0f * __builtin_amdgcn_rcpf(4.3711388e-8f);
        const float t1 = y4 - wi, t2 = y4 + wi;
        const float i1 = __builtin_amdgcn_rcpf(fmaf(t1, t1, wz));
        const float i2 = __builtin_amdgcn_rcpf(fmaf(t2, t2, wz));
        const float u1 = t1 * i1, u2 = t2 * i2;
        const float Sr = wx * (i1 + i2);
        const float Si = -(u1 + u2);
        const float Dr = u1 - u2;
        const float Di = wx * (i1 - i2);
        float e0 = v00r * Sr + v00i * Dr, e1 = v00r * Si + v00i * Di;
        float e2 = v01r * Sr + v01i * Dr, e3 = v01r * Si + v01i * Di;
        float e4 = v10r * Sr + v10i * Dr, e5 = v10r * Si + v10i * Di;
        float e6 = v11r * Sr + v11i * Dr, e7 = v11r * Si + v11i * Di;
        #pragma unroll
        for (int m = 1; m < 64; m <<= 1) {
            e0 += __shfl_xor(e0, m);  e1 += __shfl_xor(e1, m);
            e2 += __shfl_xor(e2, m);  e3 += __shfl_xor(e3, m);
            e4 += __shfl_xor(e4, m);  e5 += __shfl_xor(e5, m);
            e6 += __shfl_xor(e6, m);  e7 += __shfl_xor(e7, m);
        }
        if (tid == 0) {
            const float a00r = e0 * dt, a00i = e1 * dt;
            const float a01r = e2 * dt, a01i = e3 * dt;
            const float a10r = e4 * dt, a10i = e5 * dt;
            const float a11r = e6 * dt, a11i = e7 * dt;
            const float numr = a01r * a10r - a01i * a10i;
            const float numi = a01r * a10i + a01i * a10r;
            const float dwr = 1.f + a11r, dwi = a11i;
            const float idw = __builtin_amdgcn_rcpf(dwr * dwr + dwi * dwi);
            const float qr = (numr * dwr + numi * dwi) * idw;
            const float qi = (numi * dwr - numr * dwi) * idw;
            const float kfr = a00r - qr, kfi = a00i - qi;
            const float fi  = 0.5f * y4;
            nyq[h] = make_float2(kfr - kfi * fi, kfi + kfr * fi);
        }
    }
}

// ---------------- Kernel B: pack + radix-4 Stockham iFFT + store -------------
__global__ __launch_bounds__(NTB)
void ifft_phase(float* __restrict__ io, const float2* __restrict__ nyq)
{
    __shared__ float2 sA[NHALF];
    __shared__ float2 sB[NHALF];

    const int h   = blockIdx.x;
    const int tid = threadIdx.x;
    float2* grow = (float2*)(io + (size_t)h * LL);

    // pack irfft(L) into complex iFFT(L/2), natural order:
    // Z[k] = (1/L)[(G[k]+conj(G[N-k])) + i*e^{+2pi i k/L}(G[k]-conj(G[N-k]))]
    #pragma unroll
    for (int ki = 0; ki < 4; ++ki) {
        const int k = tid + NTB * ki;
        const float2 Gk = grow[k];
        const float2 Gn = (k == 0) ? nyq[h] : grow[NHALF - k];
        const float Ar = Gk.x + Gn.x, Ai = Gk.y - Gn.y;
        const float Br = Gk.x - Gn.x, Bi = Gk.y + Gn.y;
        const float rev = (float)k * 1.220703125e-4f;   // k/8192
        const float cw = __builtin_amdgcn_cosf(rev);
        const float sw = __builtin_amdgcn_sinf(rev);
        const float sc = 1.0f / (float)LL;
        sA[k] = make_float2((Ar - cw * Bi - sw * Br) * sc,
                            (Ai + cw * Br - sw * Bi) * sc);
    }
    __syncthreads();

    // 6 radix-4 Stockham stages (inverse FFT, e^{+i} twiddles), ping-pong sA<->sB
    float2* pin  = sA;
    float2* pout = sB;
    #pragma unroll
    for (int s = 0; s < 6; ++s) {
        const int ls2 = 2 * s;
        const int Ls  = 1 << ls2;
        const int j   = tid;
        const int k   = j & (Ls - 1);
        const int tb  = k << (10 - ls2);
        const float fr = (float)tb * 2.44140625e-4f;    // tb/4096 revolutions
        const float c1 = __builtin_amdgcn_cosf(fr);
        const float s1 = __builtin_amdgcn_sinf(fr);
        const float c2 = __builtin_amdgcn_cosf(2.0f * fr);
        const float s2 = __builtin_amdgcn_sinf(2.0f * fr);
        const float c3 = __builtin_amdgcn_cosf(3.0f * fr);
        const float s3 = __builtin_amdgcn_sinf(3.0f * fr);
        float2 u0 = pin[j];
        float2 u1 = pin[j + 1024];
        float2 u2 = pin[j + 2048];
        float2 u3 = pin[j + 3072];
        float a, b;
        a = u1.x * c1 - u1.y * s1;  b = u1.x * s1 + u1.y * c1;  u1 = make_float2(a, b);
        a = u2.x * c2 - u2.y * s2;  b = u2.x * s2 + u2.y * c2;  u2 = make_float2(a, b);
        a = u3.x * c3 - u3.y * s3;  b = u3.x * s3 + u3.y * c3;  u3 = make_float2(a, b);
        const float t0r = u0.x + u2.x, t0i = u0.y + u2.y;
        const float t1r = u0.x - u2.x, t1i = u0.y - u2.y;
        const float t2r = u1.x + u3.x, t2i = u1.y + u3.y;
        const float t3r = u3.y - u1.y, t3i = u1.x - u3.x;   // i*(u1-u3)
        const int ob = ((j - k) << 2) + k;
        pout[ob]          = make_float2(t0r + t2r, t0i + t2i);
        pout[ob + Ls]     = make_float2(t1r + t3r, t1i + t3i);
        pout[ob + 2 * Ls] = make_float2(t0r - t2r, t0i - t2i);
        pout[ob + 3 * Ls] = make_float2(t1r - t3r, t1i - t3i);
        float2* tmp = pin; pin = pout; pout = tmp;
        __syncthreads();
    }

    // final data lands in sA; x[2j]=Re, x[2j+1]=Im -> coalesced float2 store
    #pragma unroll
    for (int ji = 0; ji < 4; ++ji) {
        const int j = tid + NTB * ji;
        grow[j] = sA[j];
    }
}

extern "C" void kernel_launch(void* const* d_in, const int* in_sizes, int n_in,
                              void* d_out, int out_size, void* d_ws, size_t ws_size,
                              hipStream_t stream) {
    const float* w   = (const float*)d_in[0];
    const float* p   = (const float*)d_in[1];
    const float* q   = (const float*)d_in[2];
    const float* B   = (const float*)d_in[3];
    const float* C   = (const float*)d_in[4];
    const float* ldt = (const float*)d_in[5];
    float*  spec = (float*)d_out;          // spectrum staged in-place in d_out
    float2* nyq  = (float2*)d_ws;          // 256 * 8 B Nyquist bins

    dim3 gridA(16, NUM_H);
    cauchy_phase<<<gridA, NTA, 0, stream>>>(w, p, q, B, C, ldt, spec, nyq);
    ifft_phase<<<NUM_H, NTB, 0, stream>>>(spec, nyq);
}

// Round 7
// 56.769 us; speedup vs baseline: 1.0880x; 1.0880x over previous
//
#include <hip/hip_runtime.h>
#include <math.h>

#define NUM_H 256
#define NP    64        // poles per h
#define LL    8192      // sequence length
#define NHALF 4096      // LL/2 (complex FFT size)
#define NTA   256       // threads, Cauchy kernel
#define NTB   1024      // threads, FFT kernel

typedef float v2f __attribute__((ext_vector_type(2)));

// v_sin_f32 / v_cos_f32 take input in REVOLUTIONS (D = sin(S0 * 2pi)).

// Per pole-pair constants (each float4 holds two packed-pair lanes {e,o}).
struct PolePair {
    float4 k0;   // {nwisq, c1}   nwisq = -wi^2 ; c1 = wz^2 + 2*wz*wi^2
    float4 k1;   // {c2, c3}      c2 = 2*wz     ; c3 = 2*(wi^2+wz)
    float4 k2;   // {wi, wz}
    float4 k3;   // {nwz, w2i}    nwz = -wz     ; w2i = 2*wi
    float2 k4;   // {wx}          wx = -wr
    float2 pad;
    float4 v0;   // {v00r, v00i}  B*conj(C)
    float4 v1;   // {v01r, v01i}  p*conj(C)
    float4 v2;   // {v10r, v10i}  B*conj(q)
    float4 v3;   // {v11r, v11i}  p*conj(q)
};

// ---------------- Kernel A: Cauchy sum + Woodbury -> spectrum ----------------
// Each lane owns one bin; inner loop processes a pole PAIR per iteration with
// VOP3P packed-f32 inline asm -- modifier-free (neg_lo/neg_hi semantics on
// pk_f32 are unverified and round 6 implicated them; all signs are folded
// into pre-negated constants instead).
//
// Identities (z = i*y, wd = wr + i*wi, wx=-wr, wz=wr^2, t1=y-wi, t2=y+wi,
// d1=t1^2+wz, d2=t2^2+wz, g=y^2-wi^2):
//   dd   = d1*d2 = g^2 + 2*wz*y^2 + (wz^2 + 2*wz*wi^2)   [all terms >= 0]
//   d1+d2 = 2*y^2 + c3        d2-d1 = 4*y*wi
//   u1+u2 = 2*y*(g+wz)        u1-u2 = 2*wi*(g-wz)
__global__ __launch_bounds__(NTA, 4)
void cauchy_phase(const float* __restrict__ w_ri,
                  const float* __restrict__ p_ri,
                  const float* __restrict__ q_ri,
                  const float* __restrict__ B_ri,
                  const float* __restrict__ C_ri,
                  const float* __restrict__ log_dt,
                  float*       __restrict__ spec,   // (H, 4096) float2 rows (= d_out)
                  float2*      __restrict__ nyq)    // (H,) Nyquist bins (= d_ws)
{
    __shared__ PolePair s_pp[NP / 2];

    const int h     = blockIdx.y;
    const int chunk = blockIdx.x;      // 16 chunks of 256 bins
    const int tid   = threadIdx.x;
    const float dt  = expf(log_dt[h]);

    if (tid < NP) {
        const int n = tid;
        const int k = n >> 1, o = n & 1;
        const float2 w = ((const float2*)w_ri)[h * NP + n];
        const float2 p = ((const float2*)p_ri)[h * NP + n];
        const float2 q = ((const float2*)q_ri)[h * NP + n];
        const float2 B = ((const float2*)B_ri)[h * NP + n];
        const float2 C = ((const float2*)C_ri)[h * NP + n];
        const float wr = w.x * dt, wi = w.y * dt;
        const float wz = wr * wr, wisq = wi * wi;
        float* base = (float*)&s_pp[k];
        base[0 + o]  = -wisq;                       // nwisq
        base[2 + o]  = wz * wz + 2.f * wz * wisq;   // c1
        base[4 + o]  = 2.f * wz;                    // c2
        base[6 + o]  = 2.f * (wisq + wz);           // c3
        base[8 + o]  = wi;
        base[10 + o] = wz;
        base[12 + o] = -wz;                         // nwz
        base[14 + o] = 2.f * wi;                    // w2i
        base[16 + o] = -wr;                         // wx
        base[18 + o] = 0.f;                         // pad
        base[20 + o] = B.x * C.x + B.y * C.y;       // v00r
        base[22 + o] = B.y * C.x - B.x * C.y;       // v00i
        base[24 + o] = p.x * C.x + p.y * C.y;       // v01r
        base[26 + o] = p.y * C.x - p.x * C.y;       // v01i
        base[28 + o] = B.x * q.x + B.y * q.y;       // v10r
        base[30 + o] = B.y * q.x - B.x * q.y;       // v10i
        base[32 + o] = p.x * q.x + p.y * q.y;       // v11r
        base[34 + o] = p.y * q.x - p.x * q.y;       // v11i
    }
    __syncthreads();

    const int l = (chunk << 8) + tid;       // 0..4095
    // y = Im(z) = 2*tan(pi*l/L); rev = l/16384 (exact dyadic)
    const float rev = (float)l * 6.103515625e-5f;
    const float sn  = __builtin_amdgcn_sinf(rev);
    const float cn  = fmaxf(__builtin_amdgcn_cosf(rev), 4.3711388e-8f);
    const float y   = 2.0f * sn * __builtin_amdgcn_rcpf(cn);
    const float ysq = y * y;
    const v2f yA   = {ysq, ysq};                 // y^2
    const v2f yA2  = {2.f * ysq, 2.f * ysq};     // 2*y^2
    const v2f y4s  = {4.f * y, 4.f * y};         // 4*y
    const v2f ny2s = {-2.f * y, -2.f * y};       // -2*y

    v2f a0 = 0.f, a1 = 0.f, a2 = 0.f, a3 = 0.f;
    v2f a4 = 0.f, a5 = 0.f, a6 = 0.f, a7 = 0.f;
    #pragma unroll 2
    for (int k = 0; k < NP / 2; ++k) {
        const float4 k0 = s_pp[k].k0;
        const float4 k1 = s_pp[k].k1;
        const float4 k2 = s_pp[k].k2;
        const float4 k3 = s_pp[k].k3;
        const float2 k4 = s_pp[k].k4;
        const float4 v0 = s_pp[k].v0;
        const float4 v1 = s_pp[k].v1;
        const float4 v2 = s_pp[k].v2;
        const float4 v3 = s_pp[k].v3;
        const v2f nwisq = {k0.x, k0.y}, c1  = {k0.z, k0.w};
        const v2f c2    = {k1.x, k1.y}, c3  = {k1.z, k1.w};
        const v2f wi2   = {k2.x, k2.y}, wz2 = {k2.z, k2.w};
        const v2f nwz2  = {k3.x, k3.y}, w2i = {k3.z, k3.w};
        const v2f wx2   = {k4.x, k4.y};
        const v2f v00r2 = {v0.x, v0.y}, v00i2 = {v0.z, v0.w};
        const v2f v01r2 = {v1.x, v1.y}, v01i2 = {v1.z, v1.w};
        const v2f v10r2 = {v2.x, v2.y}, v10i2 = {v2.z, v2.w};
        const v2f v11r2 = {v3.x, v3.y}, v11i2 = {v3.z, v3.w};

        v2f g, inner, dd;
        asm("v_pk_add_f32 %0, %3, %4\n\t"        // g = y^2 + (-wi^2)
            "v_pk_fma_f32 %1, %5, %3, %6\n\t"    // inner = c2*y^2 + c1
            "v_pk_fma_f32 %2, %0, %0, %1"        // dd = g*g + inner
            : "=&v"(g), "=&v"(inner), "=&v"(dd)
            : "v"(yA), "v"(nwisq), "v"(c2), "v"(c1));

        const v2f ir = {__builtin_amdgcn_rcpf(dd.x), __builtin_amdgcn_rcpf(dd.y)};

        v2f Sr, Di, SiN, Dr, scr;
        asm("v_pk_add_f32 %0, %5, %6\n\t"        // SI  = 2y^2 + c3      (d1+d2)
            "v_pk_mul_f32 %1, %7, %8\n\t"        // DI  = 4y * wi        (d2-d1)
            "v_pk_add_f32 %2, %9, %10\n\t"       // h1  = g + wz
            "v_pk_add_f32 %3, %9, %11\n\t"       // h2  = g + (-wz)
            "v_pk_mul_f32 %2, %12, %2\n\t"       // SPn = -2y * h1       (-(u1+u2)*dd)
            "v_pk_mul_f32 %3, %13, %3\n\t"       // SM  = 2wi * h2       ((u1-u2)*dd)
            "v_pk_mul_f32 %4, %14, %15\n\t"      // irx = wx * ir
            "v_pk_mul_f32 %0, %0, %4\n\t"        // Sr  = SI * irx
            "v_pk_mul_f32 %1, %1, %4\n\t"        // Di  = DI * irx
            "v_pk_mul_f32 %3, %3, %15\n\t"       // Dr  = SM * ir
            "v_pk_mul_f32 %2, %2, %15"           // SiN = SPn * ir       (= Si)
            : "=&v"(Sr), "=&v"(Di), "=&v"(SiN), "=&v"(Dr), "=&v"(scr)
            : "v"(yA2), "v"(c3), "v"(y4s), "v"(wi2), "v"(g), "v"(wz2),
              "v"(nwz2), "v"(ny2s), "v"(w2i), "v"(wx2), "v"(ir));

        asm("v_pk_fma_f32 %0, %12, %8, %0\n\t"   // a0 += v00r*Sr
            "v_pk_fma_f32 %0, %13, %10, %0\n\t"  // a0 += v00i*Dr
            "v_pk_fma_f32 %1, %12, %9, %1\n\t"   // a1 += v00r*SiN
            "v_pk_fma_f32 %1, %13, %11, %1\n\t"  // a1 += v00i*Di
            "v_pk_fma_f32 %2, %14, %8, %2\n\t"
            "v_pk_fma_f32 %2, %15, %10, %2\n\t"
            "v_pk_fma_f32 %3, %14, %9, %3\n\t"
            "v_pk_fma_f32 %3, %15, %11, %3\n\t"
            "v_pk_fma_f32 %4, %16, %8, %4\n\t"
            "v_pk_fma_f32 %4, %17, %10, %4\n\t"
            "v_pk_fma_f32 %5, %16, %9, %5\n\t"
            "v_pk_fma_f32 %5, %17, %11, %5\n\t"
            "v_pk_fma_f32 %6, %18, %8, %6\n\t"
            "v_pk_fma_f32 %6, %19, %10, %6\n\t"
            "v_pk_fma_f32 %7, %18, %9, %7\n\t"
            "v_pk_fma_f32 %7, %19, %11, %7"
            : "+v"(a0), "+v"(a1), "+v"(a2), "+v"(a3),
              "+v"(a4), "+v"(a5), "+v"(a6), "+v"(a7)
            : "v"(Sr), "v"(SiN), "v"(Dr), "v"(Di),
              "v"(v00r2), "v"(v00i2), "v"(v01r2), "v"(v01i2),
              "v"(v10r2), "v"(v10i2), "v"(v11r2), "v"(v11i2));
    }

    // horizontal add over the pole-pair halves, then Woodbury
    {
        const float a00r = (a0.x + a0.y) * dt, a00i = (a1.x + a1.y) * dt;
        const float a01r = (a2.x + a2.y) * dt, a01i = (a3.x + a3.y) * dt;
        const float a10r = (a4.x + a4.y) * dt, a10i = (a5.x + a5.y) * dt;
        const float a11r = (a6.x + a6.y) * dt, a11i = (a7.x + a7.y) * dt;
        const float numr = a01r * a10r - a01i * a10i;
        const float numi = a01r * a10i + a01i * a10r;
        const float dwr = 1.f + a11r, dwi = a11i;
        const float idw = __builtin_amdgcn_rcpf(dwr * dwr + dwi * dwi);
        const float qr = (numr * dwr + numi * dwi) * idw;
        const float qi = (numi * dwr - numr * dwi) * idw;
        const float kfr = a00r - qr, kfi = a00i - qi;
        const float fi  = 0.5f * y;        // 2/(1+nodes) = 1 + i*tan(pi*l/L)
        float2* grow = (float2*)(spec + (size_t)h * LL);
        grow[l] = make_float2(kfr - kfi * fi, kfi + kfr * fi);
    }

    // ---- Nyquist bin l=4096: one pole per lane of wave 0 of chunk 15 ----
    if (chunk == 15 && tid < 64) {
        const int n = tid;
        const int k = n >> 1, o = n & 1;
        const float* base = (const float*)&s_pp[k];
        const float wi = base[8 + o];
        const float wz = base[10 + o];
        const float wx = base[16 + o];
        const float v00r = base[20 + o], v00i = base[22 + o];
        const float v01r = base[24 + o], v01i = base[26 + o];
        const float v10r = base[28 + o], v10i = base[30 + o];
        const float v11r = base[32 + o], v11i = base[34 + o];
        // rev = 0.25 -> cos = 0 exactly; clamp reproduces reference's f32 z ~ 4.58e7
        const float y4 = 2.0f * __builtin_amdgcn_rcpf(4.3711388e-8f);
        const float t1 = y4 - wi, t2 = y4 + wi;
        const float i1 = __builtin_amdgcn_rcpf(fmaf(t1, t1, wz));
        const float i2 = __builtin_amdgcn_rcpf(fmaf(t2, t2, wz));
        const float u1 = t1 * i1, u2 = t2 * i2;
        const float Sr = wx * (i1 + i2);
        const float Si = -(u1 + u2);
        const float Dr = u1 - u2;
        const float Di = wx * (i1 - i2);
        float e0 = v00r * Sr + v00i * Dr, e1 = v00r * Si + v00i * Di;
        float e2 = v01r * Sr + v01i * Dr, e3 = v01r * Si + v01i * Di;
        float e4 = v10r * Sr + v10i * Dr, e5 = v10r * Si + v10i * Di;
        float e6 = v11r * Sr + v11i * Dr, e7 = v11r * Si + v11i * Di;
        #pragma unroll
        for (int m = 1; m < 64; m <<= 1) {
            e0 += __shfl_xor(e0, m);  e1 += __shfl_xor(e1, m);
            e2 += __shfl_xor(e2, m);  e3 += __shfl_xor(e3, m);
            e4 += __shfl_xor(e4, m);  e5 += __shfl_xor(e5, m);
            e6 += __shfl_xor(e6, m);  e7 += __shfl_xor(e7, m);
        }
        if (tid == 0) {
            const float a00r = e0 * dt, a00i = e1 * dt;
            const float a01r = e2 * dt, a01i = e3 * dt;
            const float a10r = e4 * dt, a10i = e5 * dt;
            const float a11r = e6 * dt, a11i = e7 * dt;
            const float numr = a01r * a10r - a01i * a10i;
            const float numi = a01r * a10i + a01i * a10r;
            const float dwr = 1.f + a11r, dwi = a11i;
            const float idw = __builtin_amdgcn_rcpf(dwr * dwr + dwi * dwi);
            const float qr = (numr * dwr + numi * dwi) * idw;
            const float qi = (numi * dwr - numr * dwi) * idw;
            const float kfr = a00r - qr, kfi = a00i - qi;
            const float fi  = 0.5f * y4;
            nyq[h] = make_float2(kfr - kfi * fi, kfi + kfr * fi);
        }
    }
}

// ---------------- Kernel B: pack + radix-4 Stockham iFFT + store -------------
__global__ __launch_bounds__(NTB)
void ifft_phase(float* __restrict__ io, const float2* __restrict__ nyq)
{
    __shared__ float2 sA[NHALF];
    __shared__ float2 sB[NHALF];

    const int h   = blockIdx.x;
    const int tid = threadIdx.x;
    float2* grow = (float2*)(io + (size_t)h * LL);

    // pack irfft(L) into complex iFFT(L/2), natural order:
    // Z[k] = (1/L)[(G[k]+conj(G[N-k])) + i*e^{+2pi i k/L}(G[k]-conj(G[N-k]))]
    #pragma unroll
    for (int ki = 0; ki < 4; ++ki) {
        const int k = tid + NTB * ki;
        const float2 Gk = grow[k];
        const float2 Gn = (k == 0) ? nyq[h] : grow[NHALF - k];
        const float Ar = Gk.x + Gn.x, Ai = Gk.y - Gn.y;
        const float Br = Gk.x - Gn.x, Bi = Gk.y + Gn.y;
        const float rev = (float)k * 1.220703125e-4f;   // k/8192
        const float cw = __builtin_amdgcn_cosf(rev);
        const float sw = __builtin_amdgcn_sinf(rev);
        const float sc = 1.0f / (float)LL;
        sA[k] = make_float2((Ar - cw * Bi - sw * Br) * sc,
                            (Ai + cw * Br - sw * Bi) * sc);
    }
    __syncthreads();

    // 6 radix-4 Stockham stages (inverse FFT, e^{+i} twiddles), ping-pong sA<->sB
    float2* pin  = sA;
    float2* pout = sB;
    #pragma unroll
    for (int s = 0; s < 6; ++s) {
        const int ls2 = 2 * s;
        const int Ls  = 1 << ls2;
        const int j   = tid;
        const int k   = j & (Ls - 1);
        const int tb  = k << (10 - ls2);
        const float fr = (float)tb * 2.44140625e-4f;    // tb/4096 revolutions
        const float c1 = __builtin_amdgcn_cosf(fr);
        const float s1 = __builtin_amdgcn_sinf(fr);
        const float c2 = __builtin_amdgcn_cosf(2.0f * fr);
        const float s2 = __builtin_amdgcn_sinf(2.0f * fr);
        const float c3 = __builtin_amdgcn_cosf(3.0f * fr);
        const float s3 = __builtin_amdgcn_sinf(3.0f * fr);
        float2 u0 = pin[j];
        float2 u1 = pin[j + 1024];
        float2 u2 = pin[j + 2048];
        float2 u3 = pin[j + 3072];
        float a, b;
        a = u1.x * c1 - u1.y * s1;  b = u1.x * s1 + u1.y * c1;  u1 = make_float2(a, b);
        a = u2.x * c2 - u2.y * s2;  b = u2.x * s2 + u2.y * c2;  u2 = make_float2(a, b);
        a = u3.x * c3 - u3.y * s3;  b = u3.x * s3 + u3.y * c3;  u3 = make_float2(a, b);
        const float t0r = u0.x + u2.x, t0i = u0.y + u2.y;
        const float t1r = u0.x - u2.x, t1i = u0.y - u2.y;
        const float t2r = u1.x + u3.x, t2i = u1.y + u3.y;
        const float t3r = u3.y - u1.y, t3i = u1.x - u3.x;   // i*(u1-u3)
        const int ob = ((j - k) << 2) + k;
        pout[ob]          = make_float2(t0r + t2r, t0i + t2i);
        pout[ob + Ls]     = make_float2(t1r + t3r, t1i + t3i);
        pout[ob + 2 * Ls] = make_float2(t0r - t2r, t0i - t2i);
        pout[ob + 3 * Ls] = make_float2(t1r - t3r, t1i - t3i);
        float2* tmp = pin; pin = pout; pout = tmp;
        __syncthreads();
    }

    // final data lands in sA; x[2j]=Re, x[2j+1]=Im -> coalesced float2 store
    #pragma unroll
    for (int ji = 0; ji < 4; ++ji) {
        const int j = tid + NTB * ji;
        grow[j] = sA[j];
    }
}

extern "C" void kernel_launch(void* const* d_in, const int* in_sizes, int n_in,
                              void* d_out, int out_size, void* d_ws, size_t ws_size,
                              hipStream_t stream) {
    const float* w   = (const float*)d_in[0];
    const float* p   = (const float*)d_in[1];
    const float* q   = (const float*)d_in[2];
    const float* B   = (const float*)d_in[3];
    const float* C   = (const float*)d_in[4];
    const float* ldt = (const float*)d_in[5];
    float*  spec = (float*)d_out;          // spectrum staged in-place in d_out
    float2* nyq  = (float2*)d_ws;          // 256 * 8 B Nyquist bins

    dim3 gridA(16, NUM_H);
    cauchy_phase<<<gridA, NTA, 0, stream>>>(w, p, q, B, C, ldt, spec, nyq);
    ifft_phase<<<NUM_H, NTB, 0, stream>>>(spec, nyq);
}